// Round 1
// baseline (3506.470 us; speedup 1.0000x reference)
//
#include <hip/hip_runtime.h>
#include <hip/hip_fp16.h>
#include <math.h>

typedef _Float16 half8  __attribute__((ext_vector_type(8)));
typedef _Float16 half4v __attribute__((ext_vector_type(4)));
typedef float    f32x4  __attribute__((ext_vector_type(4)));

#define MFMA_F16 __builtin_amdgcn_mfma_f32_16x16x32_f16

namespace {

constexpr int M_ROWS    = 128;                       // rows per block
constexpr int H_STRIDE  = 264;                       // halves; 256 + 8 pad (keeps 16B align, 2-way banks)
constexpr int PE_STRIDE = 72;                        // halves; 64 + 8 pad
constexpr int H_OFF     = 0;
constexpr int PEX_OFF   = M_ROWS * H_STRIDE;         // 33792
constexpr int PED_OFF   = PEX_OFF + M_ROWS * PE_STRIDE; // 43008
constexpr int LDS_HALVES = PED_OFF + M_ROWS * PE_STRIDE; // 52224 (104448 B)
constexpr size_t LDS_BYTES = (size_t)LDS_HALVES * sizeof(_Float16);

// Layer order: g1_0..g1_4, g2_0..g2_2, c_0, c_1, sig
constexpr int KCH_A[11] = {2,8,8,8,8,10,8,8,10,8,8};
constexpr int OFF_A[11] = {0,16384,81920,147456,212992,278528,360448,425984,491520,573440,577536};
constexpr int TOTAL_W   = 581632;   // fp16 elements in swizzled blob

struct Ptr11 { const float* p[11]; };

// ---------------------------------------------------------------------------
// Weight pre-swizzle: blob[(nt*KCH + kc)*512 + lane*8 + j] =
//   W[remap(kc*32 + (lane>>4)*8 + j)][nt*16 + (lane&15)]  as fp16, 0 if padded.
// A-fragment layout for mfma_f32_16x16x32_f16: row i = lane&15, k = quad*8+j.
// ---------------------------------------------------------------------------
__global__ void prep_kernel(Ptr11 wp, _Float16* __restrict__ ws) {
  int tid = blockIdx.x * blockDim.x + threadIdx.x;
  if (tid >= TOTAL_W) return;
  int L = 0;
#pragma unroll
  for (int i = 1; i < 11; ++i) if (tid >= OFF_A[i]) L = i;
  int e    = tid - OFF_A[L];
  int j    = e & 7;
  int lane = (e >> 3) & 63;
  int blk  = e >> 9;
  int kch  = KCH_A[L];
  int kc   = blk % kch;
  int kpad = kc * 32 + ((lane >> 4) << 3) + j;
  int n    = ((blk / kch) << 4) + (lane & 15);
  int k;
  if      (L == 0) k = (kpad < 63) ? kpad : -1;                               // g1_0: din 63 pad->64
  else if (L == 5) k = (kpad < 64) ? ((kpad < 63) ? kpad : -1) : kpad - 1;    // g2_0: [pe_x 63|f1 256]
  else if (L == 8) k = (kpad < 64) ? ((kpad < 39) ? kpad : -1) : kpad - 25;   // c_0:  [pe_d 39|f2 256]
  else             k = kpad;                                                  // din 256 exact
  int dout = (L == 9) ? 3 : ((L == 10) ? 1 : 256);
  float v = 0.f;
  if (k >= 0 && n < dout) v = wp.p[L][k * dout + n];
  ws[tid] = (_Float16)v;
}

// ---------------------------------------------------------------------------
// One 256-out linear layer (optionally with a 64-wide PE K-segment first).
// Wave w (0..7) computes output features [w*32, w*32+32) for all 128 rows.
// D = A*B with A = W^T fragment (global), B = H^T fragment (LDS) so that
// D[n][m] C-layout gives each lane 4 consecutive n for one row m -> b64 write.
// ---------------------------------------------------------------------------
__device__ __noinline__ void do_layer(_Float16* lds,
                                      const _Float16* __restrict__ blob,
                                      const float* __restrict__ bias,
                                      int pe_off, int pe_ch, int h_ch,
                                      bool relu, int w, int lane) {
  const int l15  = lane & 15;
  const int quad = lane >> 4;
  const int KCH  = pe_ch + h_ch;

  f32x4 acc[8][2];
#pragma unroll
  for (int mt = 0; mt < 8; ++mt) {
    acc[mt][0] = (f32x4)0.f;
    acc[mt][1] = (f32x4)0.f;
  }

  half8 a[2][2];
  half8 b[2][8];

  auto load_frags = [&](int buf, int kcg) {
    int lbase, stride, kloc;
    if (kcg < pe_ch) { lbase = pe_off; stride = PE_STRIDE; kloc = kcg; }
    else             { lbase = H_OFF;  stride = H_STRIDE;  kloc = kcg - pe_ch; }
#pragma unroll
    for (int nt = 0; nt < 2; ++nt)
      a[buf][nt] = *(const half8*)(blob + ((((w * 2 + nt) * KCH) + kcg) * 64 + lane) * 8);
#pragma unroll
    for (int mt = 0; mt < 8; ++mt)
      b[buf][mt] = *(const half8*)(lds + lbase + (mt * 16 + l15) * stride + kloc * 32 + quad * 8);
  };

  load_frags(0, 0);
  for (int kcg = 0; kcg < KCH; ++kcg) {
    int cur = kcg & 1;
    if (kcg + 1 < KCH) load_frags(cur ^ 1, kcg + 1);
#pragma unroll
    for (int mt = 0; mt < 8; ++mt)
#pragma unroll
      for (int nt = 0; nt < 2; ++nt)
        acc[mt][nt] = MFMA_F16(a[cur][nt], b[cur][mt], acc[mt][nt], 0, 0, 0);
  }

  __syncthreads();   // all waves done READING H before anyone overwrites it
#pragma unroll
  for (int mt = 0; mt < 8; ++mt) {
    int m = mt * 16 + l15;
#pragma unroll
    for (int nt = 0; nt < 2; ++nt) {
      int n0 = w * 32 + nt * 16 + quad * 4;
      f32x4 v = acc[mt][nt];
      f32x4 bb = *(const f32x4*)(bias + n0);
      v += bb;
      if (relu) {
        v.x = fmaxf(v.x, 0.f); v.y = fmaxf(v.y, 0.f);
        v.z = fmaxf(v.z, 0.f); v.w = fmaxf(v.w, 0.f);
      }
      half4v hv = { (_Float16)v.x, (_Float16)v.y, (_Float16)v.z, (_Float16)v.w };
      *(half4v*)(lds + H_OFF + m * H_STRIDE + n0) = hv;
    }
  }
  __syncthreads();
}

// Small head (sig / c_1): NT=1 blob, K=256 over H; wave 0 only, covers all 128 rows.
__device__ void small_head(const _Float16* lds, const _Float16* __restrict__ blob,
                           int lane, f32x4 res[8]) {
  const int l15  = lane & 15;
  const int quad = lane >> 4;
#pragma unroll
  for (int mt = 0; mt < 8; ++mt) res[mt] = (f32x4)0.f;
  for (int kc = 0; kc < 8; ++kc) {
    half8 a = *(const half8*)(blob + (kc * 64 + lane) * 8);
#pragma unroll
    for (int mt = 0; mt < 8; ++mt) {
      half8 b = *(const half8*)(lds + H_OFF + (mt * 16 + l15) * H_STRIDE + kc * 32 + quad * 8);
      res[mt] = MFMA_F16(a, b, res[mt], 0, 0, 0);
    }
  }
}

__global__ __launch_bounds__(512, 2) void nerf_kernel(
    const _Float16* __restrict__ ws, const float* __restrict__ x,
    const float* __restrict__ dirp, Ptr11 bp, float* __restrict__ out) {
  extern __shared__ _Float16 lds[];
  const int tid  = threadIdx.x;
  const int lane = tid & 63;
  const int w    = tid >> 6;       // wave 0..7
  const int l15  = lane & 15;
  const int quad = lane >> 4;
  const int row0 = blockIdx.x * M_ROWS;

  // ---- stage x / direction into (future) H region as fp32 ----
  float* xs = (float*)(lds + H_OFF);   // [0..383] = x rows, [384..767] = dir rows
  for (int i = tid; i < 768; i += 512)
    xs[i] = (i < 384) ? x[row0 * 3 + i] : dirp[row0 * 3 + (i - 384)];
  __syncthreads();

  // ---- positional encodings -> pe_x [128][64] (63 real), pe_d [128][64] (39 real) ----
  for (int i = tid; i < M_ROWS * 64; i += 512) {
    int r = i >> 6, f = i & 63;
    float vx = 0.f, vd = 0.f;
    if (f < 3) {
      vx = xs[r * 3 + f];
      vd = xs[384 + r * 3 + f];
    } else {
      int g = f - 3, li = g / 6, rem = g % 6, s = rem / 3, c = rem % 3;
      if (f < 63) {
        float ax = xs[r * 3 + c] * (float)(1 << li);
        vx = s ? cosf(ax) : sinf(ax);
      }
      if (f < 39) {
        float ad = xs[384 + r * 3 + c] * (float)(1 << li);
        vd = s ? cosf(ad) : sinf(ad);
      }
    }
    lds[PEX_OFF + r * PE_STRIDE + f] = (_Float16)vx;
    lds[PED_OFF + r * PE_STRIDE + f] = (_Float16)vd;
  }
  __syncthreads();

  // ---- G1: 63->256, 256->256 x4 (ReLU on all but last) ----
  do_layer(lds, ws + OFF_A[0], bp.p[0], PEX_OFF, 2, 0, true,  w, lane);
  do_layer(lds, ws + OFF_A[1], bp.p[1], 0,       0, 8, true,  w, lane);
  do_layer(lds, ws + OFF_A[2], bp.p[2], 0,       0, 8, true,  w, lane);
  do_layer(lds, ws + OFF_A[3], bp.p[3], 0,       0, 8, true,  w, lane);
  do_layer(lds, ws + OFF_A[4], bp.p[4], 0,       0, 8, false, w, lane);  // f1
  // ---- G2: [pe_x|f1] -> 256, 256->256, 256->256 (no ReLU on last) ----
  do_layer(lds, ws + OFF_A[5], bp.p[5], PEX_OFF, 2, 8, true,  w, lane);
  do_layer(lds, ws + OFF_A[6], bp.p[6], 0,       0, 8, true,  w, lane);
  do_layer(lds, ws + OFF_A[7], bp.p[7], 0,       0, 8, false, w, lane);  // f2

  // ---- sigma head (reads f2; must precede c_0's overwrite of H) ----
  float sigv[8];
  if (w == 0) {
    f32x4 sa[8];
    small_head(lds, ws + OFF_A[10], lane, sa);
    float sb = bp.p[10][0];
#pragma unroll
    for (int mt = 0; mt < 8; ++mt) sigv[mt] = sa[mt][0] + sb;  // valid in quad==0 lanes
  }

  // ---- color: [pe_d|f2] -> 256 (ReLU), then 256 -> 3 ----
  do_layer(lds, ws + OFF_A[8], bp.p[8], PED_OFF, 2, 8, true, w, lane);
  if (w == 0) {
    f32x4 ca[8];
    small_head(lds, ws + OFF_A[9], lane, ca);
    float b0 = bp.p[9][0], b1 = bp.p[9][1], b2 = bp.p[9][2];
    if (quad == 0) {
#pragma unroll
      for (int mt = 0; mt < 8; ++mt) {
        f32x4 o = { ca[mt][0] + b0, ca[mt][1] + b1, ca[mt][2] + b2, sigv[mt] };
        *(f32x4*)(out + (size_t)(row0 + mt * 16 + l15) * 4) = o;
      }
    }
  }
}

}  // namespace

extern "C" void kernel_launch(void* const* d_in, const int* in_sizes, int n_in,
                              void* d_out, int out_size, void* d_ws, size_t ws_size,
                              hipStream_t stream) {
  const float* x   = (const float*)d_in[0];
  const float* dir = (const float*)d_in[1];
  Ptr11 wp, bp;
  for (int i = 0; i < 11; ++i) {
    wp.p[i] = (const float*)d_in[2 + 2 * i];
    bp.p[i] = (const float*)d_in[3 + 2 * i];
  }
  _Float16* ws = (_Float16*)d_ws;
  float* out = (float*)d_out;

  static bool attr_set = []() {
    hipFuncSetAttribute((const void*)nerf_kernel,
                        hipFuncAttributeMaxDynamicSharedMemorySize, (int)LDS_BYTES);
    return true;
  }();
  (void)attr_set;
  // idempotent; also call unconditionally so behavior is identical every launch
  hipFuncSetAttribute((const void*)nerf_kernel,
                      hipFuncAttributeMaxDynamicSharedMemorySize, (int)LDS_BYTES);

  prep_kernel<<<TOTAL_W / 256, 256, 0, stream>>>(wp, ws);
  nerf_kernel<<<262144 / M_ROWS, 512, LDS_BYTES, stream>>>(ws, x, dir, bp, out);
}

// Round 2
// 437.545 us; speedup vs baseline: 8.0140x; 8.0140x over previous
//
#include <hip/hip_runtime.h>
#include <hip/hip_fp16.h>
#include <math.h>

typedef _Float16 half8  __attribute__((ext_vector_type(8)));
typedef _Float16 half4v __attribute__((ext_vector_type(4)));
typedef float    f32x4  __attribute__((ext_vector_type(4)));

#define MFMA_F16 __builtin_amdgcn_mfma_f32_16x16x32_f16

namespace {

constexpr int M_ROWS    = 128;                       // rows per block
constexpr int H_STRIDE  = 264;                       // halves; 132 words, 132%32=4, (132/4)%8 odd -> 2-way max
constexpr int PE_STRIDE = 72;                        // halves; 36 words, same property
constexpr int H_OFF     = 0;
constexpr int PEX_OFF   = M_ROWS * H_STRIDE;         // 33792
constexpr int PED_OFF   = PEX_OFF + M_ROWS * PE_STRIDE; // 43008
constexpr int LDS_HALVES = PED_OFF + M_ROWS * PE_STRIDE; // 52224 (104448 B)
constexpr size_t LDS_BYTES = (size_t)LDS_HALVES * sizeof(_Float16);

// Layer order: g1_0..g1_4, g2_0..g2_2, c_0, c_1, sig
constexpr int KCH_A[11] = {2,8,8,8,8,10,8,8,10,8,8};
constexpr int OFF_A[11] = {0,16384,81920,147456,212992,278528,360448,425984,491520,573440,577536};
constexpr int TOTAL_W   = 581632;   // fp16 elements in swizzled blob

struct Ptr11 { const float* p[11]; };

// ---------------------------------------------------------------------------
// Weight pre-swizzle: blob[(nt*KCH + kc)*512 + lane*8 + j] =
//   W[remap(kc*32 + (lane>>4)*8 + j)][nt*16 + (lane&15)]  as fp16, 0 if padded.
// A-fragment layout for mfma_f32_16x16x32_f16: row i = lane&15, k = quad*8+j.
// ---------------------------------------------------------------------------
__global__ void prep_kernel(Ptr11 wp, _Float16* __restrict__ ws) {
  int tid = blockIdx.x * blockDim.x + threadIdx.x;
  if (tid >= TOTAL_W) return;
  int L = 0;
#pragma unroll
  for (int i = 1; i < 11; ++i) if (tid >= OFF_A[i]) L = i;
  int e    = tid - OFF_A[L];
  int j    = e & 7;
  int lane = (e >> 3) & 63;
  int blk  = e >> 9;
  int kch  = KCH_A[L];
  int kc   = blk % kch;
  int kpad = kc * 32 + ((lane >> 4) << 3) + j;
  int n    = ((blk / kch) << 4) + (lane & 15);
  int k;
  if      (L == 0) k = (kpad < 63) ? kpad : -1;                               // g1_0: din 63 pad->64
  else if (L == 5) k = (kpad < 64) ? ((kpad < 63) ? kpad : -1) : kpad - 1;    // g2_0: [pe_x 63|f1 256]
  else if (L == 8) k = (kpad < 64) ? ((kpad < 39) ? kpad : -1) : kpad - 25;   // c_0:  [pe_d 39|f2 256]
  else             k = kpad;                                                  // din 256 exact
  int dout = (L == 9) ? 3 : ((L == 10) ? 1 : 256);
  float v = 0.f;
  if (k >= 0 && n < dout) v = wp.p[L][k * dout + n];
  ws[tid] = (_Float16)v;
}

// ---------------------------------------------------------------------------
// One 256-out linear layer. Compile-time shape (PE_CH pe-chunks then H_CH
// H-chunks of K=32) so the K-loop fully unrolls and the two pipeline buffers
// have constant indices -> all fragments stay in VGPRs (R1: dynamic-index
// arrays spilled to scratch, 17 GB of HBM traffic, 76 VGPRs).
// Wave w computes output features [w*32, w*32+32) for all 128 rows.
// D = A*B, A = W^T fragment (global), B = H^T fragment (LDS): C-layout gives
// each lane 4 consecutive out-features for one row -> packed 8B LDS write.
// ---------------------------------------------------------------------------
template <int PE_CH, int H_CH, bool RELU>
__device__ __forceinline__ void do_layer(_Float16* lds,
                                         const _Float16* __restrict__ blob,
                                         const float* __restrict__ bias,
                                         int pe_off, int w, int lane) {
  constexpr int KCH = PE_CH + H_CH;
  const int l15  = lane & 15;
  const int quad = lane >> 4;

  f32x4 acc[8][2];
#pragma unroll
  for (int mt = 0; mt < 8; ++mt) {
    acc[mt][0] = (f32x4)0.f;
    acc[mt][1] = (f32x4)0.f;
  }

  half8 aA[2], bA[8], aB[2], bB[8];

#define LOAD_FRAGS(abuf, bbuf, KCG)                                           \
  {                                                                           \
    _Pragma("unroll") for (int nt = 0; nt < 2; ++nt)                          \
        abuf[nt] = *(const half8*)(blob +                                     \
            ((((w * 2 + nt) * KCH) + (KCG)) * 64 + lane) * 8);                \
    const _Float16* lb;                                                       \
    int stride;                                                               \
    if ((KCG) < PE_CH) {                                                      \
      lb = lds + pe_off + (KCG) * 32;                                         \
      stride = PE_STRIDE;                                                     \
    } else {                                                                  \
      lb = lds + H_OFF + ((KCG)-PE_CH) * 32;                                  \
      stride = H_STRIDE;                                                      \
    }                                                                         \
    _Pragma("unroll") for (int mt = 0; mt < 8; ++mt)                          \
        bbuf[mt] = *(const half8*)(lb + (mt * 16 + l15) * stride + quad * 8); \
  }

#define DO_MFMA(abuf, bbuf)                                                   \
  {                                                                           \
    _Pragma("unroll") for (int mt = 0; mt < 8; ++mt)                          \
        _Pragma("unroll") for (int nt = 0; nt < 2; ++nt)                      \
            acc[mt][nt] = MFMA_F16(abuf[nt], bbuf[mt], acc[mt][nt], 0, 0, 0); \
  }

  LOAD_FRAGS(aA, bA, 0)
#pragma unroll
  for (int kcg = 0; kcg < KCH; ++kcg) {
    if ((kcg & 1) == 0) {
      if (kcg + 1 < KCH) LOAD_FRAGS(aB, bB, kcg + 1)
      DO_MFMA(aA, bA)
    } else {
      if (kcg + 1 < KCH) LOAD_FRAGS(aA, bA, kcg + 1)
      DO_MFMA(aB, bB)
    }
  }
#undef LOAD_FRAGS
#undef DO_MFMA

  __syncthreads();   // all waves done READING H before anyone overwrites it
#pragma unroll
  for (int mt = 0; mt < 8; ++mt) {
    int m = mt * 16 + l15;
#pragma unroll
    for (int nt = 0; nt < 2; ++nt) {
      int n0 = w * 32 + nt * 16 + quad * 4;
      f32x4 v = acc[mt][nt];
      f32x4 bb = *(const f32x4*)(bias + n0);
      v += bb;
      if (RELU) {
        v.x = fmaxf(v.x, 0.f); v.y = fmaxf(v.y, 0.f);
        v.z = fmaxf(v.z, 0.f); v.w = fmaxf(v.w, 0.f);
      }
      half4v hv = { (_Float16)v.x, (_Float16)v.y, (_Float16)v.z, (_Float16)v.w };
      *(half4v*)(lds + H_OFF + m * H_STRIDE + n0) = hv;
    }
  }
  __syncthreads();
}

// Small head (sig / c_1): NT=1 blob, K=256 over H; wave 0 only, all 128 rows.
__device__ __forceinline__ void small_head(const _Float16* lds,
                                           const _Float16* __restrict__ blob,
                                           int lane, f32x4 res[8]) {
  const int l15  = lane & 15;
  const int quad = lane >> 4;
#pragma unroll
  for (int mt = 0; mt < 8; ++mt) res[mt] = (f32x4)0.f;
#pragma unroll
  for (int kc = 0; kc < 8; ++kc) {
    half8 a = *(const half8*)(blob + (kc * 64 + lane) * 8);
#pragma unroll
    for (int mt = 0; mt < 8; ++mt) {
      half8 b = *(const half8*)(lds + H_OFF + (mt * 16 + l15) * H_STRIDE + kc * 32 + quad * 8);
      res[mt] = MFMA_F16(a, b, res[mt], 0, 0, 0);
    }
  }
}

__global__ __launch_bounds__(512, 2) void nerf_kernel(
    const _Float16* __restrict__ ws, const float* __restrict__ x,
    const float* __restrict__ dirp, Ptr11 bp, float* __restrict__ out) {
  extern __shared__ _Float16 lds[];
  const int tid  = threadIdx.x;
  const int lane = tid & 63;
  const int w    = tid >> 6;       // wave 0..7
  const int l15  = lane & 15;
  const int quad = lane >> 4;
  const int row0 = blockIdx.x * M_ROWS;

  // ---- stage x / direction into (future) H region as fp32 ----
  float* xs = (float*)(lds + H_OFF);   // [0..383] = x rows, [384..767] = dir rows
  for (int i = tid; i < 768; i += 512)
    xs[i] = (i < 384) ? x[row0 * 3 + i] : dirp[row0 * 3 + (i - 384)];
  __syncthreads();

  // ---- positional encodings -> pe_x [128][64] (63 real), pe_d [128][64] (39 real) ----
  for (int i = tid; i < M_ROWS * 64; i += 512) {
    int r = i >> 6, f = i & 63;
    float vx = 0.f, vd = 0.f;
    if (f < 3) {
      vx = xs[r * 3 + f];
      vd = xs[384 + r * 3 + f];
    } else {
      int g = f - 3, li = g / 6, rem = g % 6, s = rem / 3, c = rem % 3;
      if (f < 63) {
        float ax = xs[r * 3 + c] * (float)(1 << li);
        vx = s ? cosf(ax) : sinf(ax);
      }
      if (f < 39) {
        float ad = xs[384 + r * 3 + c] * (float)(1 << li);
        vd = s ? cosf(ad) : sinf(ad);
      }
    }
    lds[PEX_OFF + r * PE_STRIDE + f] = (_Float16)vx;
    lds[PED_OFF + r * PE_STRIDE + f] = (_Float16)vd;
  }
  __syncthreads();

  // ---- G1: 63->256, 256->256 x4 (ReLU on all but last) ----
  do_layer<2, 0, true >(lds, ws + OFF_A[0], bp.p[0], PEX_OFF, w, lane);
  do_layer<0, 8, true >(lds, ws + OFF_A[1], bp.p[1], 0,       w, lane);
  do_layer<0, 8, true >(lds, ws + OFF_A[2], bp.p[2], 0,       w, lane);
  do_layer<0, 8, true >(lds, ws + OFF_A[3], bp.p[3], 0,       w, lane);
  do_layer<0, 8, false>(lds, ws + OFF_A[4], bp.p[4], 0,       w, lane);  // f1
  // ---- G2: [pe_x|f1] -> 256, 256->256, 256->256 (no ReLU on last) ----
  do_layer<2, 8, true >(lds, ws + OFF_A[5], bp.p[5], PEX_OFF, w, lane);
  do_layer<0, 8, true >(lds, ws + OFF_A[6], bp.p[6], 0,       w, lane);
  do_layer<0, 8, false>(lds, ws + OFF_A[7], bp.p[7], 0,       w, lane);  // f2

  // ---- sigma head (reads f2; must precede c_0's overwrite of H) ----
  float sigv[8];
  if (w == 0) {
    f32x4 sa[8];
    small_head(lds, ws + OFF_A[10], lane, sa);
    float sb = bp.p[10][0];
#pragma unroll
    for (int mt = 0; mt < 8; ++mt) sigv[mt] = sa[mt][0] + sb;  // valid in quad==0 lanes
  }

  // ---- color: [pe_d|f2] -> 256 (ReLU), then 256 -> 3 ----
  do_layer<2, 8, true>(lds, ws + OFF_A[8], bp.p[8], PED_OFF, w, lane);
  if (w == 0) {
    f32x4 ca[8];
    small_head(lds, ws + OFF_A[9], lane, ca);
    float b0 = bp.p[9][0], b1 = bp.p[9][1], b2 = bp.p[9][2];
    if (quad == 0) {
#pragma unroll
      for (int mt = 0; mt < 8; ++mt) {
        f32x4 o = { ca[mt][0] + b0, ca[mt][1] + b1, ca[mt][2] + b2, sigv[mt] };
        *(f32x4*)(out + (size_t)(row0 + mt * 16 + l15) * 4) = o;
      }
    }
  }
}

}  // namespace

extern "C" void kernel_launch(void* const* d_in, const int* in_sizes, int n_in,
                              void* d_out, int out_size, void* d_ws, size_t ws_size,
                              hipStream_t stream) {
  const float* x   = (const float*)d_in[0];
  const float* dir = (const float*)d_in[1];
  Ptr11 wp, bp;
  for (int i = 0; i < 11; ++i) {
    wp.p[i] = (const float*)d_in[2 + 2 * i];
    bp.p[i] = (const float*)d_in[3 + 2 * i];
  }
  _Float16* ws = (_Float16*)d_ws;
  float* out = (float*)d_out;

  hipFuncSetAttribute((const void*)nerf_kernel,
                      hipFuncAttributeMaxDynamicSharedMemorySize, (int)LDS_BYTES);

  prep_kernel<<<TOTAL_W / 256, 256, 0, stream>>>(wp, ws);
  nerf_kernel<<<262144 / M_ROWS, 512, LDS_BYTES, stream>>>(ws, x, dir, bp, out);
}